// Round 4
// baseline (1034.406 us; speedup 1.0000x reference)
//
#include <hip/hip_runtime.h>
#include <hip/hip_bf16.h>

// ---------- types & helpers ----------
typedef __attribute__((ext_vector_type(4))) float  f32x4;
typedef __attribute__((ext_vector_type(8))) __bf16 bf16x8;
typedef __attribute__((ext_vector_type(8))) unsigned short u16x8;

typedef const __attribute__((address_space(1))) void gas_void;
typedef __attribute__((address_space(3))) void las_void;

__device__ __forceinline__ unsigned short f2bf(float x) {
    unsigned u = __builtin_bit_cast(unsigned, x);
    u += 0x7fffu + ((u >> 16) & 1u);          // round-to-nearest-even
    return (unsigned short)(u >> 16);
}
__device__ __forceinline__ float bf2f(unsigned short h) {
    unsigned u = ((unsigned)h) << 16;
    return __builtin_bit_cast(float, u);
}
__device__ __forceinline__ void gload_lds16(const void* g, void* l) {
    __builtin_amdgcn_global_load_lds((gas_void*)g, (las_void*)l, 16, 0, 0);
}

#define WAITVM(N) asm volatile("s_waitcnt vmcnt(" #N ")" ::: "memory")

// ---------- kernel 1: fp32 -> bf16 convert (vectorized) ----------
__global__ void k_f32_to_bf16(const float* __restrict__ in,
                              unsigned short* __restrict__ out, int n4) {
    int i = blockIdx.x * blockDim.x + threadIdx.x;
    if (i < n4) {
        float4 v = ((const float4*)in)[i];
        ushort4 o;
        o.x = f2bf(v.x); o.y = f2bf(v.y); o.z = f2bf(v.z); o.w = f2bf(v.w);
        ((ushort4*)out)[i] = o;
    }
}

// ---------- kernel 2: W [K=1024][N=3072] fp32 -> Wt [N][K] bf16 ----------
__global__ void k_transpose_w(const float* __restrict__ W,
                              unsigned short* __restrict__ Wt,
                              int K, int N) {
    __shared__ unsigned short tile[32][33];
    int n0 = blockIdx.x * 32, k0 = blockIdx.y * 32;
    int tx = threadIdx.x, ty = threadIdx.y;   // 32 x 8
#pragma unroll
    for (int i = 0; i < 4; i++) {
        int kk = ty + i * 8;
        tile[kk][tx] = f2bf(W[(size_t)(k0 + kk) * N + n0 + tx]);
    }
    __syncthreads();
#pragma unroll
    for (int i = 0; i < 4; i++) {
        int nn = ty + i * 8;
        Wt[(size_t)(n0 + nn) * K + k0 + tx] = tile[tx][nn];
    }
}

// ---------- kernel 3: Vrow [b][S][D] -> Vt [b][D][S] bf16 ----------
__global__ void k_transpose_v(const unsigned short* __restrict__ Vrow,
                              unsigned short* __restrict__ Vt) {
    __shared__ unsigned short tile[32][33];
    int b = blockIdx.z;
    int s0 = blockIdx.x * 32, d0 = blockIdx.y * 32;
    int tx = threadIdx.x, ty = threadIdx.y;   // 32 x 8
#pragma unroll
    for (int i = 0; i < 4; i++) {
        int ss = ty + i * 8;
        tile[ss][tx] = Vrow[((size_t)(b * 4096 + s0 + ss)) * 1024 + d0 + tx];
    }
    __syncthreads();
#pragma unroll
    for (int i = 0; i < 4; i++) {
        int dd = ty + i * 8;
        Vt[((size_t)b * 1024 + d0 + dd) * 4096 + s0 + tx] = tile[tx][dd];
    }
}

// ============================================================================
// 256x256 8-phase GEMM, BK=64, 8 waves (2M x 4N), 512 thr.
// R4 fixes vs R3: (1) __launch_bounds__(512,1) -- R3's (512,2) capped regs at
// 128 -> acc spill -> 1.26GB scratch writes; (2) swizzle re-derived for
// 128B-row layout: byte ^= (row&7)<<4 (R3's ((byte>>9)&1)<<5 only spread 2
// bank positions).  Same involution on stage source and ds_read (rule #21).
// vmcnt ledger (2 loads/half, stage order A0,B0,A1,B1 one half/phase):
//   p1 vmcnt(4) {A0,B0}; p2 vmcnt(4) A1; p3 vmcnt(4) B1; p4 none.
//   Last tile: 4 -> 2 -> 0.
// MODE 1: bf16 C.  MODE 2: bf16 routed {Q|K} into C, V into Vp, +bias.
// ============================================================================
template <int MODE>
__global__ __launch_bounds__(512, 1) void k_gemm256(
        const unsigned short* __restrict__ A, int lda,
        const unsigned short* __restrict__ Bt, int ldb,
        void* __restrict__ C, int ldc,
        unsigned short* __restrict__ Vp,
        const float* __restrict__ bias,
        int K, float alpha, long sA, long sB, long sC) {
    __shared__ __align__(16) unsigned short As[2][16384];
    __shared__ __align__(16) unsigned short Bs[2][16384];

    const int z = blockIdx.z;
    A  += (size_t)z * sA;
    Bt += (size_t)z * sB;

    // XCD-aware bijective swizzle (requires nwg % 8 == 0)
    const int nwg  = gridDim.x * gridDim.y;
    const int flat = blockIdx.y * gridDim.x + blockIdx.x;
    const int swzb = (flat & 7) * (nwg >> 3) + (flat >> 3);
    const int m0   = (swzb / gridDim.x) * 256;
    const int n0   = (swzb % gridDim.x) * 256;

    const int tid  = threadIdx.x;
    const int lane = tid & 63;
    const int wid  = tid >> 6;      // 0..7
    const int wm   = wid >> 2;      // 0..1
    const int wn   = wid & 3;       // 0..3
    const int l15  = lane & 15;
    const int l4   = lane >> 4;     // 0..3

    f32x4 acc[8][4] = {};

    // ---- staging: one half (16KB) = 2 x gload_lds16 per thread ----
    // physical byte phi (linear wave write order) <-> logical byte lam:
    //   lam = phi ^ ((row&7)<<4), row = phi>>7 (XOR touches bits 4-6 only)
    auto stageA = [&](int b, int h, int kt) {
#pragma unroll
        for (int c = 0; c < 2; c++) {
            int phi  = c * 8192 + tid * 16;
            int rowp = phi >> 7;                               // 0..127
            int lam  = phi ^ ((rowp & 7) << 4);
            int kel  = (lam & 127) >> 1;                       // 0..63
            int grow = m0 + (rowp >> 6) * 128 + h * 64 + (rowp & 63);
            gload_lds16(A + (size_t)grow * lda + kt * 64 + kel,
                        (char*)As + b * 32768 + h * 16384 + c * 8192 + (wid << 10));
        }
    };
    auto stageB = [&](int b, int h, int kt) {
#pragma unroll
        for (int c = 0; c < 2; c++) {
            int phi  = c * 8192 + tid * 16;
            int rowp = phi >> 7;
            int lam  = phi ^ ((rowp & 7) << 4);
            int kel  = (lam & 127) >> 1;
            int gnrow = n0 + (rowp >> 5) * 64 + h * 32 + (rowp & 31);
            gload_lds16(Bt + (size_t)gnrow * ldb + kt * 64 + kel,
                        (char*)Bs + b * 32768 + h * 16384 + c * 8192 + (wid << 10));
        }
    };
    // ---- fragment reads (swizzled ds_read_b128) ----
    auto rdA = [&](int b, int qm, int mf, int kk) -> bf16x8 {
        int rowp = wm * 64 + mf * 16 + l15;                    // within half
        int lam  = qm * 16384 + rowp * 128 + kk * 64 + l4 * 16;
        int ads  = lam ^ ((rowp & 7) << 4);
        return *(const bf16x8*)((const char*)As + b * 32768 + ads);
    };
    auto rdB = [&](int b, int qn, int nf, int kk) -> bf16x8 {
        int rowp = wn * 32 + nf * 16 + l15;
        int lam  = qn * 16384 + rowp * 128 + kk * 64 + l4 * 16;
        int ads  = lam ^ ((rowp & 7) << 4);
        return *(const bf16x8*)((const char*)Bs + b * 32768 + ads);
    };

#define MM(I, J, X, Y) \
    acc[I][J] = __builtin_amdgcn_mfma_f32_16x16x32_bf16((X), (Y), acc[I][J], 0, 0, 0)

#define PHASE(BUF, QM, QN, WAIT_STMT, STG_STMT)                                \
    do {                                                                       \
        WAIT_STMT;                                                             \
        __builtin_amdgcn_s_barrier();                                          \
        __builtin_amdgcn_sched_barrier(0);                                     \
        STG_STMT;                                                              \
        bf16x8 a00 = rdA(BUF, QM, 0, 0), a01 = rdA(BUF, QM, 0, 1);             \
        bf16x8 a10 = rdA(BUF, QM, 1, 0), a11 = rdA(BUF, QM, 1, 1);             \
        bf16x8 a20 = rdA(BUF, QM, 2, 0), a21 = rdA(BUF, QM, 2, 1);             \
        bf16x8 a30 = rdA(BUF, QM, 3, 0), a31 = rdA(BUF, QM, 3, 1);             \
        bf16x8 b00 = rdB(BUF, QN, 0, 0), b01 = rdB(BUF, QN, 0, 1);             \
        bf16x8 b10 = rdB(BUF, QN, 1, 0), b11 = rdB(BUF, QN, 1, 1);             \
        __builtin_amdgcn_s_setprio(1);                                         \
        MM(QM * 4 + 0, QN * 2 + 0, a00, b00); MM(QM * 4 + 0, QN * 2 + 0, a01, b01); \
        MM(QM * 4 + 0, QN * 2 + 1, a00, b10); MM(QM * 4 + 0, QN * 2 + 1, a01, b11); \
        MM(QM * 4 + 1, QN * 2 + 0, a10, b00); MM(QM * 4 + 1, QN * 2 + 0, a11, b01); \
        MM(QM * 4 + 1, QN * 2 + 1, a10, b10); MM(QM * 4 + 1, QN * 2 + 1, a11, b11); \
        MM(QM * 4 + 2, QN * 2 + 0, a20, b00); MM(QM * 4 + 2, QN * 2 + 0, a21, b01); \
        MM(QM * 4 + 2, QN * 2 + 1, a20, b10); MM(QM * 4 + 2, QN * 2 + 1, a21, b11); \
        MM(QM * 4 + 3, QN * 2 + 0, a30, b00); MM(QM * 4 + 3, QN * 2 + 0, a31, b01); \
        MM(QM * 4 + 3, QN * 2 + 1, a30, b10); MM(QM * 4 + 3, QN * 2 + 1, a31, b11); \
        __builtin_amdgcn_s_setprio(0);                                         \
    } while (0)

    const int NT = K >> 6;
    // prologue: stage tile 0 (order A0,B0,A1,B1 — ledger depends on it)
    stageA(0, 0, 0); stageB(0, 0, 0); stageA(0, 1, 0); stageB(0, 1, 0);

    for (int t = 0; t < NT; t++) {
        const int cb = t & 1, nb = cb ^ 1;
        if (t + 1 < NT) {
            PHASE(cb, 0, 0, WAITVM(4), stageA(nb, 0, t + 1));
            PHASE(cb, 1, 0, WAITVM(4), stageB(nb, 0, t + 1));
            PHASE(cb, 0, 1, WAITVM(4), stageA(nb, 1, t + 1));
            PHASE(cb, 1, 1, (void)0,   stageB(nb, 1, t + 1));
        } else {
            PHASE(cb, 0, 0, WAITVM(4), (void)0);
            PHASE(cb, 1, 0, WAITVM(2), (void)0);
            PHASE(cb, 0, 1, WAITVM(0), (void)0);
            PHASE(cb, 1, 1, (void)0,   (void)0);
        }
    }
#undef PHASE
#undef MM

    // ---- epilogue: C/D layout col = lane&15, row = (lane>>4)*4 + r ----
#pragma unroll
    for (int qm = 0; qm < 2; qm++)
#pragma unroll
    for (int mf = 0; mf < 4; mf++) {
        const int row = m0 + wm * 128 + qm * 64 + mf * 16 + l4 * 4;
#pragma unroll
        for (int qn = 0; qn < 2; qn++)
#pragma unroll
        for (int nf = 0; nf < 2; nf++) {
            const int col = n0 + wn * 64 + qn * 32 + nf * 16 + l15;
            const float bv = (MODE == 2) ? bias[col] : 0.0f;
            const f32x4 av = acc[qm * 4 + mf][qn * 2 + nf];
#pragma unroll
            for (int r = 0; r < 4; r++) {
                const float v = av[r] * alpha + bv;
                if (MODE == 1) {
                    ((unsigned short*)C)[(size_t)z * sC + (size_t)(row + r) * ldc + col] = f2bf(v);
                } else {
                    const int lc = col & 1023;
                    if (col < 2048)
                        ((unsigned short*)C)[(size_t)(col >> 10) * 8388608 +
                                             (size_t)(row + r) * 1024 + lc] = f2bf(v);
                    else
                        Vp[(size_t)(row + r) * 1024 + lc] = f2bf(v);
                }
            }
        }
    }
}

// ---------- m97-style 128x128 GEMM (fp32 out) for PV, + XCD swizzle ----------
__global__ void k_gemm_bt_f32(const unsigned short* __restrict__ A, int lda,
                              const unsigned short* __restrict__ Bt, int ldb,
                              float* __restrict__ C, int ldc,
                              int K, long sA, long sB, long sC) {
    __shared__ __align__(16) unsigned short As[128 * 32];
    __shared__ __align__(16) unsigned short Bs[128 * 32];

    const int z = blockIdx.z;
    A  += (size_t)z * sA;
    Bt += (size_t)z * sB;

    const int nwg  = gridDim.x * gridDim.y;      // % 8 == 0
    const int flat = blockIdx.y * gridDim.x + blockIdx.x;
    const int swzb = (flat & 7) * (nwg >> 3) + (flat >> 3);
    const int m0   = (swzb / gridDim.x) * 128;
    const int n0   = (swzb % gridDim.x) * 128;

    const int tid  = threadIdx.x;
    const int lane = tid & 63;
    const int w    = tid >> 6;
    const int wr   = w >> 1, wc = w & 1;

    f32x4 acc[4][4] = {};
    const int r0  = lane >> 2;
    const int cEl = (lane & 3) * 8;

    for (int k0 = 0; k0 < K; k0 += 32) {
#pragma unroll
        for (int i = 0; i < 2; i++) {
            const int c = w + 4 * i;
            gload_lds16(A + (size_t)(m0 + c * 16 + r0) * lda + k0 + cEl,
                        (void*)(As + c * 512));
        }
#pragma unroll
        for (int i = 0; i < 2; i++) {
            const int c = w + 4 * i;
            gload_lds16(Bt + (size_t)(n0 + c * 16 + r0) * ldb + k0 + cEl,
                        (void*)(Bs + c * 512));
        }
        __syncthreads();

        bf16x8 af[4], bfr[4];
#pragma unroll
        for (int m = 0; m < 4; m++)
            af[m] = *(const bf16x8*)&As[(wr * 64 + m * 16 + (lane & 15)) * 32 + (lane >> 4) * 8];
#pragma unroll
        for (int n = 0; n < 4; n++)
            bfr[n] = *(const bf16x8*)&Bs[(wc * 64 + n * 16 + (lane & 15)) * 32 + (lane >> 4) * 8];

#pragma unroll
        for (int m = 0; m < 4; m++)
#pragma unroll
            for (int n = 0; n < 4; n++)
                acc[m][n] = __builtin_amdgcn_mfma_f32_16x16x32_bf16(af[m], bfr[n], acc[m][n], 0, 0, 0);

        __syncthreads();
    }

#pragma unroll
    for (int m = 0; m < 4; m++) {
        const int row = m0 + wr * 64 + m * 16 + (lane >> 4) * 4;
#pragma unroll
        for (int n = 0; n < 4; n++) {
            const int col = n0 + wc * 64 + n * 16 + (lane & 15);
#pragma unroll
            for (int r = 0; r < 4; r++)
                C[(size_t)z * sC + (size_t)(row + r) * ldc + col] = acc[m][n][r];
        }
    }
}

// ---------- in-place row softmax on bf16 scores [rows][S=4096] ----------
__global__ __launch_bounds__(256) void k_softmax_inplace(unsigned short* __restrict__ P, int S) {
    __shared__ float red[8];
    const int row  = blockIdx.x;
    const int tid  = threadIdx.x;
    const int lane = tid & 63;
    const int wid  = tid >> 6;
    unsigned short* p = P + (size_t)row * S;

    float v[16];
    u16x8 h0 = *(const u16x8*)&p[tid * 16];
    u16x8 h1 = *(const u16x8*)&p[tid * 16 + 8];
    float mx = -1e30f;
#pragma unroll
    for (int j = 0; j < 8; j++) { v[j]     = bf2f(h0[j]); mx = fmaxf(mx, v[j]);     }
#pragma unroll
    for (int j = 0; j < 8; j++) { v[j + 8] = bf2f(h1[j]); mx = fmaxf(mx, v[j + 8]); }

#pragma unroll
    for (int o = 32; o >= 1; o >>= 1) mx = fmaxf(mx, __shfl_xor(mx, o));
    if (lane == 0) red[wid] = mx;
    __syncthreads();
    mx = fmaxf(fmaxf(red[0], red[1]), fmaxf(red[2], red[3]));

    float sum = 0.0f;
#pragma unroll
    for (int j = 0; j < 16; j++) { v[j] = __expf(v[j] - mx); sum += v[j]; }
#pragma unroll
    for (int o = 32; o >= 1; o >>= 1) sum += __shfl_xor(sum, o);
    if (lane == 0) red[4 + wid] = sum;
    __syncthreads();
    sum = red[4] + red[5] + red[6] + red[7];
    const float rinv = 1.0f / sum;

    u16x8 o0, o1;
#pragma unroll
    for (int j = 0; j < 8; j++) { o0[j] = f2bf(v[j] * rinv); o1[j] = f2bf(v[j + 8] * rinv); }
    *(u16x8*)&p[tid * 16]     = o0;
    *(u16x8*)&p[tid * 16 + 8] = o1;
}

// ---------- launch ----------
extern "C" void kernel_launch(void* const* d_in, const int* in_sizes, int n_in,
                              void* d_out, int out_size, void* d_ws, size_t ws_size,
                              hipStream_t stream) {
    const float* x    = (const float*)d_in[0];   // [2,4096,1024]
    const float* W    = (const float*)d_in[1];   // [1024,3072]
    const float* bias = (const float*)d_in[2];   // [3072]
    float* out        = (float*)d_out;           // [2,4096,1024]

    // ws layout (MB):  Qb@0(16)  Kb@16(16)  Vt@32(16)  xb@48(16)  Wt@64(6)  Vrow@70(16)
    // Pcat@48(64) overlays dead xb/Wt/Vrow after GEMM1+transpose_v.  Peak 112 MB.
    char* ws = (char*)d_ws;
    unsigned short* Qb   = (unsigned short*)(ws);
    unsigned short* Vt   = (unsigned short*)(ws + 33554432);
    unsigned short* xb   = (unsigned short*)(ws + 50331648);
    unsigned short* Wt   = (unsigned short*)(ws + 67108864);
    unsigned short* Vrow = (unsigned short*)(ws + 73400320);
    unsigned short* Pcat = (unsigned short*)(ws + 50331648);

    // 1. x -> bf16
    k_f32_to_bf16<<<8192, 256, 0, stream>>>(x, xb, (8192 * 1024) / 4);
    // 2. W -> Wt (bf16, transposed)
    k_transpose_w<<<dim3(96, 32), dim3(32, 8), 0, stream>>>(W, Wt, 1024, 3072);
    // 3. qkv = x*W + b  (M=8192, N=3072, K=1024), routed into Qb|Kb|Vrow
    k_gemm256<2><<<dim3(12, 32, 1), 512, 0, stream>>>(
        xb, 1024, Wt, 1024, (void*)Qb, 1024, Vrow, bias, 1024, 1.0f, 0, 0, 0);
    // 4. Vrow -> Vt
    k_transpose_v<<<dim3(128, 32, 2), dim3(32, 8), 0, stream>>>(Vrow, Vt);

    const float scale = 0.03125f;  // 1/sqrt(1024)
    // 5. scores = Q*K^T * scale  (M=N=4096, K=1024, z=2) -> bf16 Pcat
    k_gemm256<1><<<dim3(16, 16, 2), 512, 0, stream>>>(
        Qb, 1024, Qb + 8388608, 1024, (void*)Pcat, 4096, nullptr, nullptr,
        1024, scale, 4194304, 4194304, 16777216);
    // 6. row softmax in place (8192 rows)
    k_softmax_inplace<<<8192, 256, 0, stream>>>(Pcat, 4096);
    // 7. out = P * V  (M=4096, N=1024, K=4096, z=2) -> fp32
    k_gemm_bt_f32<<<dim3(8, 32, 2), 256, 0, stream>>>(
        Pcat, 4096, Vt, 4096, out, 1024, 4096, 16777216, 4194304, 4194304);
}

// Round 5
// 311.597 us; speedup vs baseline: 3.3197x; 3.3197x over previous
//
#include <hip/hip_runtime.h>
#include <hip/hip_bf16.h>

// ---------- types & helpers ----------
typedef __attribute__((ext_vector_type(4))) float  f32x4;
typedef __attribute__((ext_vector_type(8))) __bf16 bf16x8;
typedef __attribute__((ext_vector_type(8))) unsigned short u16x8;

typedef const __attribute__((address_space(1))) void gas_void;
typedef __attribute__((address_space(3))) void las_void;

__device__ __forceinline__ unsigned short f2bf(float x) {
    unsigned u = __builtin_bit_cast(unsigned, x);
    u += 0x7fffu + ((u >> 16) & 1u);          // round-to-nearest-even
    return (unsigned short)(u >> 16);
}
__device__ __forceinline__ float bf2f(unsigned short h) {
    unsigned u = ((unsigned)h) << 16;
    return __builtin_bit_cast(float, u);
}
__device__ __forceinline__ void gload_lds16(const void* g, void* l) {
    __builtin_amdgcn_global_load_lds((gas_void*)g, (las_void*)l, 16, 0, 0);
}

// ---------- kernel 1: fp32 -> bf16 convert (vectorized) ----------
__global__ void k_f32_to_bf16(const float* __restrict__ in,
                              unsigned short* __restrict__ out, int n4) {
    int i = blockIdx.x * blockDim.x + threadIdx.x;
    if (i < n4) {
        float4 v = ((const float4*)in)[i];
        ushort4 o;
        o.x = f2bf(v.x); o.y = f2bf(v.y); o.z = f2bf(v.z); o.w = f2bf(v.w);
        ((ushort4*)out)[i] = o;
    }
}

// ---------- kernel 2: W [K=1024][N=3072] fp32 -> Wt [N][K] bf16 ----------
__global__ void k_transpose_w(const float* __restrict__ W,
                              unsigned short* __restrict__ Wt,
                              int K, int N) {
    __shared__ unsigned short tile[32][33];
    int n0 = blockIdx.x * 32, k0 = blockIdx.y * 32;
    int tx = threadIdx.x, ty = threadIdx.y;   // 32 x 8
#pragma unroll
    for (int i = 0; i < 4; i++) {
        int kk = ty + i * 8;
        tile[kk][tx] = f2bf(W[(size_t)(k0 + kk) * N + n0 + tx]);
    }
    __syncthreads();
#pragma unroll
    for (int i = 0; i < 4; i++) {
        int nn = ty + i * 8;
        Wt[(size_t)(n0 + nn) * K + k0 + tx] = tile[tx][nn];
    }
}

// ---------- kernel 3: Vrow [b][S][D] -> Vt [b][D][S] bf16 ----------
__global__ void k_transpose_v(const unsigned short* __restrict__ Vrow,
                              unsigned short* __restrict__ Vt) {
    __shared__ unsigned short tile[32][33];
    int b = blockIdx.z;
    int s0 = blockIdx.x * 32, d0 = blockIdx.y * 32;
    int tx = threadIdx.x, ty = threadIdx.y;   // 32 x 8
#pragma unroll
    for (int i = 0; i < 4; i++) {
        int ss = ty + i * 8;
        tile[ss][tx] = Vrow[((size_t)(b * 4096 + s0 + ss)) * 1024 + d0 + tx];
    }
    __syncthreads();
#pragma unroll
    for (int i = 0; i < 4; i++) {
        int dd = ty + i * 8;
        Vt[((size_t)b * 1024 + d0 + dd) * 4096 + s0 + tx] = tile[tx][dd];
    }
}

// ---------- GEMM: C[M,N] = alpha * A[M,K] * Bt[N,K]^T (+ bias) ----------
// m97-style: 128x128 tile, BK=32, 4 waves (2x2 of 64x64), global_load_lds w=16,
// mfma_f32_16x16x32_bf16.  A,Bt bf16.  XCD-bijective block swizzle (nwg%8==0).
// MODE 0: fp32, split-K=2 (z = batch*2 + khalf), atomicAdd into C (C pre-zeroed).
// MODE 1: bf16 C.
// MODE 2: bf16, route cols {Q|K} into C, V into Vp, +bias.
template <int MODE>
__global__ void k_gemm_bt(const unsigned short* __restrict__ A, int lda,
                          const unsigned short* __restrict__ Bt, int ldb,
                          void* __restrict__ C, int ldc,
                          unsigned short* __restrict__ Vp,
                          const float* __restrict__ bias,
                          int K, float alpha,
                          long sA, long sB, long sC) {
    __shared__ __align__(16) unsigned short As[128 * 32];
    __shared__ __align__(16) unsigned short Bs[128 * 32];

    const int z = blockIdx.z;
    int zb = z, kOff = 0;
    if (MODE == 0) { zb = z >> 1; kOff = (z & 1) * K; }   // split-K: K = half-length
    A  += (size_t)zb * sA + kOff;
    Bt += (size_t)zb * sB + kOff;

    // XCD-aware bijective swizzle (requires nwg % 8 == 0)
    const int nwg  = gridDim.x * gridDim.y;
    const int flat = blockIdx.y * gridDim.x + blockIdx.x;
    const int swzb = (flat & 7) * (nwg >> 3) + (flat >> 3);
    const int m0   = (swzb / gridDim.x) * 128;
    const int n0   = (swzb % gridDim.x) * 128;

    const int tid  = threadIdx.x;
    const int lane = tid & 63;
    const int w    = tid >> 6;         // 0..3
    const int wr   = w >> 1, wc = w & 1;

    f32x4 acc[4][4] = {};

    const int r0  = lane >> 2;         // 0..15 (row within 16-row stripe)
    const int cEl = (lane & 3) * 8;    // k element offset 0/8/16/24

    for (int k0 = 0; k0 < K; k0 += 32) {
#pragma unroll
        for (int i = 0; i < 2; i++) {
            const int c   = w + 4 * i;
            const int row = c * 16 + r0;
            gload_lds16(A + (size_t)(m0 + row) * lda + k0 + cEl,
                        (void*)(As + c * 512));
        }
#pragma unroll
        for (int i = 0; i < 2; i++) {
            const int c   = w + 4 * i;
            const int row = c * 16 + r0;
            gload_lds16(Bt + (size_t)(n0 + row) * ldb + k0 + cEl,
                        (void*)(Bs + c * 512));
        }
        __syncthreads();   // drains vmcnt; LDS tiles ready

        bf16x8 af[4], bfr[4];
#pragma unroll
        for (int m = 0; m < 4; m++)
            af[m] = *(const bf16x8*)&As[(wr * 64 + m * 16 + (lane & 15)) * 32 + (lane >> 4) * 8];
#pragma unroll
        for (int n = 0; n < 4; n++)
            bfr[n] = *(const bf16x8*)&Bs[(wc * 64 + n * 16 + (lane & 15)) * 32 + (lane >> 4) * 8];

#pragma unroll
        for (int m = 0; m < 4; m++)
#pragma unroll
            for (int n = 0; n < 4; n++)
                acc[m][n] = __builtin_amdgcn_mfma_f32_16x16x32_bf16(af[m], bfr[n], acc[m][n], 0, 0, 0);

        __syncthreads();   // protect LDS before next-stage overwrite
    }

    // epilogue: C/D layout col = lane&15, row = (lane>>4)*4 + r
#pragma unroll
    for (int m = 0; m < 4; m++) {
        const int row = m0 + wr * 64 + m * 16 + (lane >> 4) * 4;
#pragma unroll
        for (int n = 0; n < 4; n++) {
            const int col = n0 + wc * 64 + n * 16 + (lane & 15);
            const float bv = (MODE == 2) ? bias[col] : 0.0f;
#pragma unroll
            for (int r = 0; r < 4; r++) {
                const float v = acc[m][n][r] * alpha + bv;
                if (MODE == 0) {
                    atomicAdd(&((float*)C)[(size_t)zb * sC + (size_t)(row + r) * ldc + col], v);
                } else if (MODE == 1) {
                    ((unsigned short*)C)[(size_t)zb * sC + (size_t)(row + r) * ldc + col] = f2bf(v);
                } else {
                    const int lc = col & 1023;
                    if (col < 2048) {
                        ((unsigned short*)C)[(size_t)(col >> 10) * 8388608 +
                                             (size_t)(row + r) * 1024 + lc] = f2bf(v);
                    } else {
                        Vp[(size_t)(row + r) * 1024 + lc] = f2bf(v);
                    }
                }
            }
        }
    }
}

// ---------- in-place row softmax on bf16 scores [rows][S=4096] ----------
__global__ __launch_bounds__(256) void k_softmax_inplace(unsigned short* __restrict__ P, int S) {
    __shared__ float red[8];
    const int row  = blockIdx.x;
    const int tid  = threadIdx.x;
    const int lane = tid & 63;
    const int wid  = tid >> 6;
    unsigned short* p = P + (size_t)row * S;

    float v[16];
    u16x8 h0 = *(const u16x8*)&p[tid * 16];
    u16x8 h1 = *(const u16x8*)&p[tid * 16 + 8];
    float mx = -1e30f;
#pragma unroll
    for (int j = 0; j < 8; j++) { v[j]     = bf2f(h0[j]); mx = fmaxf(mx, v[j]);     }
#pragma unroll
    for (int j = 0; j < 8; j++) { v[j + 8] = bf2f(h1[j]); mx = fmaxf(mx, v[j + 8]); }

#pragma unroll
    for (int o = 32; o >= 1; o >>= 1) mx = fmaxf(mx, __shfl_xor(mx, o));
    if (lane == 0) red[wid] = mx;
    __syncthreads();
    mx = fmaxf(fmaxf(red[0], red[1]), fmaxf(red[2], red[3]));

    float sum = 0.0f;
#pragma unroll
    for (int j = 0; j < 16; j++) { v[j] = __expf(v[j] - mx); sum += v[j]; }
#pragma unroll
    for (int o = 32; o >= 1; o >>= 1) sum += __shfl_xor(sum, o);
    if (lane == 0) red[4 + wid] = sum;
    __syncthreads();
    sum = red[4] + red[5] + red[6] + red[7];
    const float rinv = 1.0f / sum;

    u16x8 o0, o1;
#pragma unroll
    for (int j = 0; j < 8; j++) { o0[j] = f2bf(v[j] * rinv); o1[j] = f2bf(v[j + 8] * rinv); }
    *(u16x8*)&p[tid * 16]     = o0;
    *(u16x8*)&p[tid * 16 + 8] = o1;
}

// ---------- launch ----------
extern "C" void kernel_launch(void* const* d_in, const int* in_sizes, int n_in,
                              void* d_out, int out_size, void* d_ws, size_t ws_size,
                              hipStream_t stream) {
    const float* x    = (const float*)d_in[0];   // [2,4096,1024]
    const float* W    = (const float*)d_in[1];   // [1024,3072]
    const float* bias = (const float*)d_in[2];   // [3072]
    float* out        = (float*)d_out;           // [2,4096,1024]

    // ws layout (MB):  Qb@0(16)  Kb@16(16)  Vt@32(16)  xb@48(16)  Wt@64(6)  Vrow@70(16)
    // Pcat@48(64) overlays dead xb/Wt/Vrow after GEMM1+transpose_v.  Peak 112 MB.
    char* ws = (char*)d_ws;
    unsigned short* Qb   = (unsigned short*)(ws);
    unsigned short* Vt   = (unsigned short*)(ws + 33554432);
    unsigned short* xb   = (unsigned short*)(ws + 50331648);
    unsigned short* Wt   = (unsigned short*)(ws + 67108864);
    unsigned short* Vrow = (unsigned short*)(ws + 73400320);
    unsigned short* Pcat = (unsigned short*)(ws + 50331648);

    // 1. x -> bf16
    k_f32_to_bf16<<<8192, 256, 0, stream>>>(x, xb, (8192 * 1024) / 4);
    // 2. W -> Wt (bf16, transposed)
    k_transpose_w<<<dim3(96, 32), dim3(32, 8), 0, stream>>>(W, Wt, 1024, 3072);
    // 3. qkv = x*W + b  (M=8192, N=3072, K=1024), routed into Qb|Kb|Vrow
    k_gemm_bt<2><<<dim3(24, 64, 1), 256, 0, stream>>>(
        xb, 1024, Wt, 1024, (void*)Qb, 1024, Vrow, bias, 1024, 1.0f, 0, 0, 0);
    // 4. Vrow -> Vt
    k_transpose_v<<<dim3(128, 32, 2), dim3(32, 8), 0, stream>>>(Vrow, Vt);

    const float scale = 0.03125f;  // 1/sqrt(1024)
    // 5. scores = Q*K^T * scale  (M=N=4096, K=1024, z=2) -> bf16 Pcat
    k_gemm_bt<1><<<dim3(32, 32, 2), 256, 0, stream>>>(
        Qb, 1024, Qb + 8388608, 1024, (void*)Pcat, 4096, nullptr, nullptr,
        1024, scale, 4194304, 4194304, 16777216);
    // 6. row softmax in place (8192 rows)
    k_softmax_inplace<<<8192, 256, 0, stream>>>(Pcat, 4096);
    // 7. out = P * V  (M=4096, N=1024, K=4096 split 2x2048, z = batch*2+khalf)
    hipMemsetAsync(out, 0, (size_t)out_size * sizeof(float), stream);
    k_gemm_bt<0><<<dim3(8, 32, 4), 256, 0, stream>>>(
        Pcat, 4096, Vt, 4096, (void*)out, 1024, nullptr, nullptr,
        2048, 1.0f, 16777216, 4194304, 4194304);
}

// Round 6
// 278.816 us; speedup vs baseline: 3.7100x; 1.1176x over previous
//
#include <hip/hip_runtime.h>
#include <hip/hip_bf16.h>

// ---------- types & helpers ----------
typedef __attribute__((ext_vector_type(4))) float  f32x4;
typedef __attribute__((ext_vector_type(8))) __bf16 bf16x8;
typedef __attribute__((ext_vector_type(8))) unsigned short u16x8;

typedef const __attribute__((address_space(1))) void gas_void;
typedef __attribute__((address_space(3))) void las_void;

__device__ __forceinline__ unsigned short f2bf(float x) {
    unsigned u = __builtin_bit_cast(unsigned, x);
    u += 0x7fffu + ((u >> 16) & 1u);          // round-to-nearest-even
    return (unsigned short)(u >> 16);
}
__device__ __forceinline__ float bf2f(unsigned short h) {
    unsigned u = ((unsigned)h) << 16;
    return __builtin_bit_cast(float, u);
}
__device__ __forceinline__ void gload_lds16(const void* g, void* l) {
    __builtin_amdgcn_global_load_lds((gas_void*)g, (las_void*)l, 16, 0, 0);
}

#define WAITVM(N) asm volatile("s_waitcnt vmcnt(" #N ")" ::: "memory")

// ---------- kernel 1: fp32 -> bf16 convert (vectorized) ----------
__global__ void k_f32_to_bf16(const float* __restrict__ in,
                              unsigned short* __restrict__ out, int n4) {
    int i = blockIdx.x * blockDim.x + threadIdx.x;
    if (i < n4) {
        float4 v = ((const float4*)in)[i];
        ushort4 o;
        o.x = f2bf(v.x); o.y = f2bf(v.y); o.z = f2bf(v.z); o.w = f2bf(v.w);
        ((ushort4*)out)[i] = o;
    }
}

// ---------- kernel 2: W [K=1024][N=3072] fp32 -> Wt [N][K] bf16 ----------
__global__ void k_transpose_w(const float* __restrict__ W,
                              unsigned short* __restrict__ Wt,
                              int K, int N) {
    __shared__ unsigned short tile[32][33];
    int n0 = blockIdx.x * 32, k0 = blockIdx.y * 32;
    int tx = threadIdx.x, ty = threadIdx.y;   // 32 x 8
#pragma unroll
    for (int i = 0; i < 4; i++) {
        int kk = ty + i * 8;
        tile[kk][tx] = f2bf(W[(size_t)(k0 + kk) * N + n0 + tx]);
    }
    __syncthreads();
#pragma unroll
    for (int i = 0; i < 4; i++) {
        int nn = ty + i * 8;
        Wt[(size_t)(n0 + nn) * K + k0 + tx] = tile[tx][nn];
    }
}

// ---------- kernel 3: Vrow [b][S][D] -> Vt [b][D][S] bf16 ----------
__global__ void k_transpose_v(const unsigned short* __restrict__ Vrow,
                              unsigned short* __restrict__ Vt) {
    __shared__ unsigned short tile[32][33];
    int b = blockIdx.z;
    int s0 = blockIdx.x * 32, d0 = blockIdx.y * 32;
    int tx = threadIdx.x, ty = threadIdx.y;   // 32 x 8
#pragma unroll
    for (int i = 0; i < 4; i++) {
        int ss = ty + i * 8;
        tile[ss][tx] = Vrow[((size_t)(b * 4096 + s0 + ss)) * 1024 + d0 + tx];
    }
    __syncthreads();
#pragma unroll
    for (int i = 0; i < 4; i++) {
        int dd = ty + i * 8;
        Vt[((size_t)b * 1024 + d0 + dd) * 4096 + s0 + tx] = tile[tx][dd];
    }
}

// ============================================================================
// 256x256 GEMM, BK=64, 8 waves (2M x 4N), 512 thr, 2 phases per K-tile.
// Register-budget-aware redesign of the failed R3/R4 8-phase port:
//   acc f32x4[8][4] -> 128 AGPR; per-phase live arch frags: B 8x bf16x8 (32,
//   resident across the tile) + A 8x bf16x8 (32, per phase). 2 waves/SIMD
//   (512-thr block) -> 256 regs/wave cap; arch side now fits under 128.
// Schedule per tile t (cur/nxt LDS dbuf, 8 stage-instrs/thread/tile):
//   P1: issue stage A-h0,B-h0 of t+1 (4) ; vmcnt(4)  <- drains tile t's 8,
//       keeps the 4 just issued in flight (never 0 mid-loop);
//       barrier; read B all(8) + A-qm0(8); setprio1; 32 MFMA; setprio0
//   P2: issue stage A-h1,B-h1 of t+1 (4); read A-qm1(8); 32 MFMA; barrier
// LDS 128 KiB: As/Bs [2][256*64] bf16, XOR swizzle byte^=((row&7)<<4)
//   (verified conflict-free in R4), same involution on stage source + ds_read.
// MODE 1: bf16 C (alpha).  MODE 2: bf16 routed {Q|K} into C, V into Vp, +bias.
// ============================================================================
template <int MODE>
__global__ __launch_bounds__(512, 2) void k_g256(
        const unsigned short* __restrict__ A, int lda,
        const unsigned short* __restrict__ Bt, int ldb,
        void* __restrict__ C, int ldc,
        unsigned short* __restrict__ Vp,
        const float* __restrict__ bias,
        int K, float alpha, long sA, long sB, long sC) {
    __shared__ __align__(16) unsigned short As[2][16384];
    __shared__ __align__(16) unsigned short Bs[2][16384];

    const int z = blockIdx.z;
    A  += (size_t)z * sA;
    Bt += (size_t)z * sB;

    // T1: XCD-bijective block swizzle (nwg % 8 == 0)
    const int nwg  = gridDim.x * gridDim.y;
    const int flat = blockIdx.y * gridDim.x + blockIdx.x;
    const int swzb = (flat & 7) * (nwg >> 3) + (flat >> 3);
    const int m0   = (swzb / gridDim.x) * 256;
    const int n0   = (swzb % gridDim.x) * 256;

    const int tid  = threadIdx.x;
    const int lane = tid & 63;
    const int wid  = tid >> 6;      // 0..7
    const int wm   = wid >> 2;      // 0..1
    const int wn   = wid & 3;       // 0..3
    const int l15  = lane & 15;
    const int l4   = lane >> 4;     // 0..3

    f32x4 acc[8][4] = {};           // [qm*4+mf][qn*2+nf] -> 128 regs (AGPR)

    // ---- staging constants (derived once) ----
    // stage instr (h,c): rows h*128 + c*64 + wid*8 + (lane>>3); row&7 == lane>>3
    // k-elem kel = ((lane&7) ^ (lane>>3)) * 8   (swizzle-folded, lane-const)
    const int srow = wid * 8 + (lane >> 3);                 // 0..63
    const int kel  = (((lane & 7) ^ (lane >> 3)) << 3);     // 0..56
    // ds_read col byte offset per kk (swizzle-folded):
    const int c0 = ((l4 << 4)) ^ ((l15 & 7) << 4);          // kk=0
    const int c1 = (64 + (l4 << 4)) ^ ((l15 & 7) << 4);     // kk=1

    auto stageA = [&](int b, int h, int kt) {
#pragma unroll
        for (int c = 0; c < 2; c++) {
            const int r = h * 128 + c * 64 + srow;
            gload_lds16(A + (size_t)(m0 + r) * lda + kt * 64 + kel,
                        (char*)As + b * 32768 + h * 16384 + c * 8192 + (wid << 10));
        }
    };
    auto stageB = [&](int b, int h, int kt) {
#pragma unroll
        for (int c = 0; c < 2; c++) {
            const int r = h * 128 + c * 64 + srow;
            gload_lds16(Bt + (size_t)(n0 + r) * ldb + kt * 64 + kel,
                        (char*)Bs + b * 32768 + h * 16384 + c * 8192 + (wid << 10));
        }
    };

#define MM(I, J, X, Y) \
    acc[I][J] = __builtin_amdgcn_mfma_f32_16x16x32_bf16((X), (Y), acc[I][J], 0, 0, 0)

    const int NT = K >> 6;
    // prologue: stage tile 0 (A-h0, B-h0, A-h1, B-h1 = 8 instrs)
    stageA(0, 0, 0); stageB(0, 0, 0); stageA(0, 1, 0); stageB(0, 1, 0);

    for (int t = 0; t < NT; t++) {
        const int cur = t & 1, nxt = cur ^ 1;
        const char* Ab = (const char*)As + cur * 32768;
        const char* Bb = (const char*)Bs + cur * 32768;

        // ---------- P1 ----------
        if (t + 1 < NT) {
            stageA(nxt, 0, t + 1); stageB(nxt, 0, t + 1);
            WAITVM(4);
        } else {
            WAITVM(0);
        }
        __builtin_amdgcn_s_barrier();
        __builtin_amdgcn_sched_barrier(0);

        bf16x8 bfrg[2][2][2];   // [qn][nf][kk] -- resident for both phases
#pragma unroll
        for (int qn = 0; qn < 2; qn++)
#pragma unroll
        for (int nf = 0; nf < 2; nf++) {
            const int rb = (wn * 64 + qn * 32 + nf * 16 + l15) * 128;
            bfrg[qn][nf][0] = *(const bf16x8*)(Bb + rb + c0);
            bfrg[qn][nf][1] = *(const bf16x8*)(Bb + rb + c1);
        }
        {
            bf16x8 af[4][2];
#pragma unroll
            for (int mf = 0; mf < 4; mf++) {
                const int ra = (wm * 128 + 0 * 64 + mf * 16 + l15) * 128;
                af[mf][0] = *(const bf16x8*)(Ab + ra + c0);
                af[mf][1] = *(const bf16x8*)(Ab + ra + c1);
            }
            __builtin_amdgcn_s_setprio(1);
#pragma unroll
            for (int mf = 0; mf < 4; mf++)
#pragma unroll
            for (int qn = 0; qn < 2; qn++)
#pragma unroll
            for (int nf = 0; nf < 2; nf++) {
                MM(mf, qn * 2 + nf, af[mf][0], bfrg[qn][nf][0]);
                MM(mf, qn * 2 + nf, af[mf][1], bfrg[qn][nf][1]);
            }
            __builtin_amdgcn_s_setprio(0);
        }

        // ---------- P2 ----------
        if (t + 1 < NT) { stageA(nxt, 1, t + 1); stageB(nxt, 1, t + 1); }
        {
            bf16x8 af[4][2];
#pragma unroll
            for (int mf = 0; mf < 4; mf++) {
                const int ra = (wm * 128 + 1 * 64 + mf * 16 + l15) * 128;
                af[mf][0] = *(const bf16x8*)(Ab + ra + c0);
                af[mf][1] = *(const bf16x8*)(Ab + ra + c1);
            }
            __builtin_amdgcn_s_setprio(1);
#pragma unroll
            for (int mf = 0; mf < 4; mf++)
#pragma unroll
            for (int qn = 0; qn < 2; qn++)
#pragma unroll
            for (int nf = 0; nf < 2; nf++) {
                MM(4 + mf, qn * 2 + nf, af[mf][0], bfrg[qn][nf][0]);
                MM(4 + mf, qn * 2 + nf, af[mf][1], bfrg[qn][nf][1]);
            }
            __builtin_amdgcn_s_setprio(0);
        }
        __builtin_amdgcn_s_barrier();
        __builtin_amdgcn_sched_barrier(0);
    }
#undef MM

    // ---- epilogue: C/D layout col = lane&15, row = (lane>>4)*4 + r ----
#pragma unroll
    for (int qm = 0; qm < 2; qm++)
#pragma unroll
    for (int mf = 0; mf < 4; mf++) {
        const int row = m0 + wm * 128 + qm * 64 + mf * 16 + l4 * 4;
#pragma unroll
        for (int qn = 0; qn < 2; qn++)
#pragma unroll
        for (int nf = 0; nf < 2; nf++) {
            const int col = n0 + wn * 64 + qn * 32 + nf * 16 + l15;
            const float bv = (MODE == 2) ? bias[col] : 0.0f;
            const f32x4 av = acc[qm * 4 + mf][qn * 2 + nf];
#pragma unroll
            for (int r = 0; r < 4; r++) {
                const float v = av[r] * alpha + bv;
                if (MODE == 1) {
                    ((unsigned short*)C)[(size_t)z * sC + (size_t)(row + r) * ldc + col] = f2bf(v);
                } else {
                    const int lc = col & 1023;
                    if (col < 2048)
                        ((unsigned short*)C)[(size_t)(col >> 10) * 8388608 +
                                             (size_t)(row + r) * 1024 + lc] = f2bf(v);
                    else
                        Vp[(size_t)(row + r) * 1024 + lc] = f2bf(v);
                }
            }
        }
    }
}

// ---------- m97-style 128x128 GEMM (fp32 out) for PV, + XCD swizzle ----------
__global__ void k_gemm_bt_f32(const unsigned short* __restrict__ A, int lda,
                              const unsigned short* __restrict__ Bt, int ldb,
                              float* __restrict__ C, int ldc,
                              int K, long sA, long sB, long sC) {
    __shared__ __align__(16) unsigned short As[128 * 32];
    __shared__ __align__(16) unsigned short Bs[128 * 32];

    const int z = blockIdx.z;
    A  += (size_t)z * sA;
    Bt += (size_t)z * sB;

    const int nwg  = gridDim.x * gridDim.y;      // % 8 == 0
    const int flat = blockIdx.y * gridDim.x + blockIdx.x;
    const int swzb = (flat & 7) * (nwg >> 3) + (flat >> 3);
    const int m0   = (swzb / gridDim.x) * 128;
    const int n0   = (swzb % gridDim.x) * 128;

    const int tid  = threadIdx.x;
    const int lane = tid & 63;
    const int w    = tid >> 6;
    const int wr   = w >> 1, wc = w & 1;

    f32x4 acc[4][4] = {};
    const int r0  = lane >> 2;
    const int cEl = (lane & 3) * 8;

    for (int k0 = 0; k0 < K; k0 += 32) {
#pragma unroll
        for (int i = 0; i < 2; i++) {
            const int c = w + 4 * i;
            gload_lds16(A + (size_t)(m0 + c * 16 + r0) * lda + k0 + cEl,
                        (void*)(As + c * 512));
        }
#pragma unroll
        for (int i = 0; i < 2; i++) {
            const int c = w + 4 * i;
            gload_lds16(Bt + (size_t)(n0 + c * 16 + r0) * ldb + k0 + cEl,
                        (void*)(Bs + c * 512));
        }
        __syncthreads();

        bf16x8 af[4], bfr[4];
#pragma unroll
        for (int m = 0; m < 4; m++)
            af[m] = *(const bf16x8*)&As[(wr * 64 + m * 16 + (lane & 15)) * 32 + (lane >> 4) * 8];
#pragma unroll
        for (int n = 0; n < 4; n++)
            bfr[n] = *(const bf16x8*)&Bs[(wc * 64 + n * 16 + (lane & 15)) * 32 + (lane >> 4) * 8];

#pragma unroll
        for (int m = 0; m < 4; m++)
#pragma unroll
            for (int n = 0; n < 4; n++)
                acc[m][n] = __builtin_amdgcn_mfma_f32_16x16x32_bf16(af[m], bfr[n], acc[m][n], 0, 0, 0);

        __syncthreads();
    }

#pragma unroll
    for (int m = 0; m < 4; m++) {
        const int row = m0 + wr * 64 + m * 16 + (lane >> 4) * 4;
#pragma unroll
        for (int n = 0; n < 4; n++) {
            const int col = n0 + wc * 64 + n * 16 + (lane & 15);
#pragma unroll
            for (int r = 0; r < 4; r++)
                C[(size_t)z * sC + (size_t)(row + r) * ldc + col] = acc[m][n][r];
        }
    }
}

// ---------- in-place row softmax on bf16 scores [rows][S=4096] ----------
__global__ __launch_bounds__(256) void k_softmax_inplace(unsigned short* __restrict__ P, int S) {
    __shared__ float red[8];
    const int row  = blockIdx.x;
    const int tid  = threadIdx.x;
    const int lane = tid & 63;
    const int wid  = tid >> 6;
    unsigned short* p = P + (size_t)row * S;

    float v[16];
    u16x8 h0 = *(const u16x8*)&p[tid * 16];
    u16x8 h1 = *(const u16x8*)&p[tid * 16 + 8];
    float mx = -1e30f;
#pragma unroll
    for (int j = 0; j < 8; j++) { v[j]     = bf2f(h0[j]); mx = fmaxf(mx, v[j]);     }
#pragma unroll
    for (int j = 0; j < 8; j++) { v[j + 8] = bf2f(h1[j]); mx = fmaxf(mx, v[j + 8]); }

#pragma unroll
    for (int o = 32; o >= 1; o >>= 1) mx = fmaxf(mx, __shfl_xor(mx, o));
    if (lane == 0) red[wid] = mx;
    __syncthreads();
    mx = fmaxf(fmaxf(red[0], red[1]), fmaxf(red[2], red[3]));

    float sum = 0.0f;
#pragma unroll
    for (int j = 0; j < 16; j++) { v[j] = __expf(v[j] - mx); sum += v[j]; }
#pragma unroll
    for (int o = 32; o >= 1; o >>= 1) sum += __shfl_xor(sum, o);
    if (lane == 0) red[4 + wid] = sum;
    __syncthreads();
    sum = red[4] + red[5] + red[6] + red[7];
    const float rinv = 1.0f / sum;

    u16x8 o0, o1;
#pragma unroll
    for (int j = 0; j < 8; j++) { o0[j] = f2bf(v[j] * rinv); o1[j] = f2bf(v[j + 8] * rinv); }
    *(u16x8*)&p[tid * 16]     = o0;
    *(u16x8*)&p[tid * 16 + 8] = o1;
}

// ---------- launch ----------
extern "C" void kernel_launch(void* const* d_in, const int* in_sizes, int n_in,
                              void* d_out, int out_size, void* d_ws, size_t ws_size,
                              hipStream_t stream) {
    const float* x    = (const float*)d_in[0];   // [2,4096,1024]
    const float* W    = (const float*)d_in[1];   // [1024,3072]
    const float* bias = (const float*)d_in[2];   // [3072]
    float* out        = (float*)d_out;           // [2,4096,1024]

    // ws layout (MB):  Qb@0(16)  Kb@16(16)  Vt@32(16)  xb@48(16)  Wt@64(6)  Vrow@70(16)
    // Pcat@48(64) overlays dead xb/Wt/Vrow after GEMM1+transpose_v.  Peak 112 MB.
    char* ws = (char*)d_ws;
    unsigned short* Qb   = (unsigned short*)(ws);
    unsigned short* Vt   = (unsigned short*)(ws + 33554432);
    unsigned short* xb   = (unsigned short*)(ws + 50331648);
    unsigned short* Wt   = (unsigned short*)(ws + 67108864);
    unsigned short* Vrow = (unsigned short*)(ws + 73400320);
    unsigned short* Pcat = (unsigned short*)(ws + 50331648);

    // 1. x -> bf16
    k_f32_to_bf16<<<8192, 256, 0, stream>>>(x, xb, (8192 * 1024) / 4);
    // 2. W -> Wt (bf16, transposed)
    k_transpose_w<<<dim3(96, 32), dim3(32, 8), 0, stream>>>(W, Wt, 1024, 3072);
    // 3. qkv = x*W + b  (M=8192, N=3072, K=1024), routed into Qb|Kb|Vrow
    k_g256<2><<<dim3(12, 32, 1), 512, 0, stream>>>(
        xb, 1024, Wt, 1024, (void*)Qb, 1024, Vrow, bias, 1024, 1.0f, 0, 0, 0);
    // 4. Vrow -> Vt
    k_transpose_v<<<dim3(128, 32, 2), dim3(32, 8), 0, stream>>>(Vrow, Vt);

    const float scale = 0.03125f;  // 1/sqrt(1024)
    // 5. scores = Q*K^T * scale  (M=N=4096, K=1024, z=2) -> bf16 Pcat
    k_g256<1><<<dim3(16, 16, 2), 512, 0, stream>>>(
        Qb, 1024, Qb + 8388608, 1024, (void*)Pcat, 4096, nullptr, nullptr,
        1024, scale, 4194304, 4194304, 16777216);
    // 6. row softmax in place (8192 rows)
    k_softmax_inplace<<<8192, 256, 0, stream>>>(Pcat, 4096);
    // 7. out = P * V  (M=4096, N=1024, K=4096, z=2) -> fp32
    k_gemm_bt_f32<<<dim3(8, 32, 2), 256, 0, stream>>>(
        Pcat, 4096, Vt, 4096, out, 1024, 4096, 16777216, 4194304, 4194304);
}

// Round 7
// 277.645 us; speedup vs baseline: 3.7256x; 1.0042x over previous
//
#include <hip/hip_runtime.h>
#include <hip/hip_bf16.h>

// ---------- types & helpers ----------
typedef __attribute__((ext_vector_type(4))) float  f32x4;
typedef __attribute__((ext_vector_type(8))) __bf16 bf16x8;
typedef __attribute__((ext_vector_type(8))) unsigned short u16x8;

typedef const __attribute__((address_space(1))) void gas_void;
typedef __attribute__((address_space(3))) void las_void;

__device__ __forceinline__ unsigned short f2bf(float x) {
    unsigned u = __builtin_bit_cast(unsigned, x);
    u += 0x7fffu + ((u >> 16) & 1u);          // round-to-nearest-even
    return (unsigned short)(u >> 16);
}
__device__ __forceinline__ float bf2f(unsigned short h) {
    unsigned u = ((unsigned)h) << 16;
    return __builtin_bit_cast(float, u);
}
__device__ __forceinline__ void gload_lds16(const void* g, void* l) {
    __builtin_amdgcn_global_load_lds((gas_void*)g, (las_void*)l, 16, 0, 0);
}

#define WAITVM(N) asm volatile("s_waitcnt vmcnt(" #N ")" ::: "memory")

// ---------- kernel 1: fp32 -> bf16 convert (vectorized) ----------
__global__ void k_f32_to_bf16(const float* __restrict__ in,
                              unsigned short* __restrict__ out, int n4) {
    int i = blockIdx.x * blockDim.x + threadIdx.x;
    if (i < n4) {
        float4 v = ((const float4*)in)[i];
        ushort4 o;
        o.x = f2bf(v.x); o.y = f2bf(v.y); o.z = f2bf(v.z); o.w = f2bf(v.w);
        ((ushort4*)out)[i] = o;
    }
}

// ---------- kernel 2: W [K=1024][N=3072] fp32 -> Wt [N][K] bf16 ----------
__global__ void k_transpose_w(const float* __restrict__ W,
                              unsigned short* __restrict__ Wt,
                              int K, int N) {
    __shared__ unsigned short tile[32][33];
    int n0 = blockIdx.x * 32, k0 = blockIdx.y * 32;
    int tx = threadIdx.x, ty = threadIdx.y;   // 32 x 8
#pragma unroll
    for (int i = 0; i < 4; i++) {
        int kk = ty + i * 8;
        tile[kk][tx] = f2bf(W[(size_t)(k0 + kk) * N + n0 + tx]);
    }
    __syncthreads();
#pragma unroll
    for (int i = 0; i < 4; i++) {
        int nn = ty + i * 8;
        Wt[(size_t)(n0 + nn) * K + k0 + tx] = tile[tx][nn];
    }
}

// ---------- kernel 3: Vrow [b][S][D] -> Vt [b][D][S] bf16 ----------
__global__ void k_transpose_v(const unsigned short* __restrict__ Vrow,
                              unsigned short* __restrict__ Vt) {
    __shared__ unsigned short tile[32][33];
    int b = blockIdx.z;
    int s0 = blockIdx.x * 32, d0 = blockIdx.y * 32;
    int tx = threadIdx.x, ty = threadIdx.y;   // 32 x 8
#pragma unroll
    for (int i = 0; i < 4; i++) {
        int ss = ty + i * 8;
        tile[ss][tx] = Vrow[((size_t)(b * 4096 + s0 + ss)) * 1024 + d0 + tx];
    }
    __syncthreads();
#pragma unroll
    for (int i = 0; i < 4; i++) {
        int dd = ty + i * 8;
        Vt[((size_t)b * 1024 + d0 + dd) * 4096 + s0 + tx] = tile[tx][dd];
    }
}

// ============================================================================
// 256x256 GEMM, BK=64, 8 waves (2M x 4N), 512 thr, 2 phases per K-tile.
// (proven in R6; see R6 comments for schedule & ledger)
// MODE 1: bf16 C (alpha).  MODE 2: bf16 routed {Q|K} into C, V into Vp, +bias.
// ============================================================================
template <int MODE>
__global__ __launch_bounds__(512, 2) void k_g256(
        const unsigned short* __restrict__ A, int lda,
        const unsigned short* __restrict__ Bt, int ldb,
        void* __restrict__ C, int ldc,
        unsigned short* __restrict__ Vp,
        const float* __restrict__ bias,
        int K, float alpha, long sA, long sB, long sC) {
    __shared__ __align__(16) unsigned short As[2][16384];
    __shared__ __align__(16) unsigned short Bs[2][16384];

    const int z = blockIdx.z;
    A  += (size_t)z * sA;
    Bt += (size_t)z * sB;

    const int nwg  = gridDim.x * gridDim.y;
    const int flat = blockIdx.y * gridDim.x + blockIdx.x;
    const int swzb = (flat & 7) * (nwg >> 3) + (flat >> 3);
    const int m0   = (swzb / gridDim.x) * 256;
    const int n0   = (swzb % gridDim.x) * 256;

    const int tid  = threadIdx.x;
    const int lane = tid & 63;
    const int wid  = tid >> 6;      // 0..7
    const int wm   = wid >> 2;      // 0..1
    const int wn   = wid & 3;       // 0..3
    const int l15  = lane & 15;
    const int l4   = lane >> 4;     // 0..3

    f32x4 acc[8][4] = {};           // 128 AGPR

    const int srow = tid >> 3;                              // 0..63
    const int kel  = (((lane & 7) ^ (lane >> 3)) << 3);     // swizzle-folded
    const int c0 = ((l4 << 4)) ^ ((l15 & 7) << 4);
    const int c1 = (64 + (l4 << 4)) ^ ((l15 & 7) << 4);

    auto stageA = [&](int b, int h, int kt) {
#pragma unroll
        for (int c = 0; c < 2; c++) {
            const int r = h * 128 + c * 64 + srow;
            gload_lds16(A + (size_t)(m0 + r) * lda + kt * 64 + kel,
                        (char*)As + b * 32768 + h * 16384 + c * 8192 + (wid << 10));
        }
    };
    auto stageB = [&](int b, int h, int kt) {
#pragma unroll
        for (int c = 0; c < 2; c++) {
            const int r = h * 128 + c * 64 + srow;
            gload_lds16(Bt + (size_t)(n0 + r) * ldb + kt * 64 + kel,
                        (char*)Bs + b * 32768 + h * 16384 + c * 8192 + (wid << 10));
        }
    };

#define MM(I, J, X, Y) \
    acc[I][J] = __builtin_amdgcn_mfma_f32_16x16x32_bf16((X), (Y), acc[I][J], 0, 0, 0)

    const int NT = K >> 6;
    stageA(0, 0, 0); stageB(0, 0, 0); stageA(0, 1, 0); stageB(0, 1, 0);

    for (int t = 0; t < NT; t++) {
        const int cur = t & 1, nxt = cur ^ 1;
        const char* Ab = (const char*)As + cur * 32768;
        const char* Bb = (const char*)Bs + cur * 32768;

        // ---------- P1 ----------
        if (t + 1 < NT) {
            stageA(nxt, 0, t + 1); stageB(nxt, 0, t + 1);
            WAITVM(4);
        } else {
            WAITVM(0);
        }
        __builtin_amdgcn_s_barrier();
        __builtin_amdgcn_sched_barrier(0);

        bf16x8 bfrg[2][2][2];
#pragma unroll
        for (int qn = 0; qn < 2; qn++)
#pragma unroll
        for (int nf = 0; nf < 2; nf++) {
            const int rb = (wn * 64 + qn * 32 + nf * 16 + l15) * 128;
            bfrg[qn][nf][0] = *(const bf16x8*)(Bb + rb + c0);
            bfrg[qn][nf][1] = *(const bf16x8*)(Bb + rb + c1);
        }
        {
            bf16x8 af[4][2];
#pragma unroll
            for (int mf = 0; mf < 4; mf++) {
                const int ra = (wm * 128 + 0 * 64 + mf * 16 + l15) * 128;
                af[mf][0] = *(const bf16x8*)(Ab + ra + c0);
                af[mf][1] = *(const bf16x8*)(Ab + ra + c1);
            }
            __builtin_amdgcn_s_setprio(1);
#pragma unroll
            for (int mf = 0; mf < 4; mf++)
#pragma unroll
            for (int qn = 0; qn < 2; qn++)
#pragma unroll
            for (int nf = 0; nf < 2; nf++) {
                MM(mf, qn * 2 + nf, af[mf][0], bfrg[qn][nf][0]);
                MM(mf, qn * 2 + nf, af[mf][1], bfrg[qn][nf][1]);
            }
            __builtin_amdgcn_s_setprio(0);
        }

        // ---------- P2 ----------
        if (t + 1 < NT) { stageA(nxt, 1, t + 1); stageB(nxt, 1, t + 1); }
        {
            bf16x8 af[4][2];
#pragma unroll
            for (int mf = 0; mf < 4; mf++) {
                const int ra = (wm * 128 + 1 * 64 + mf * 16 + l15) * 128;
                af[mf][0] = *(const bf16x8*)(Ab + ra + c0);
                af[mf][1] = *(const bf16x8*)(Ab + ra + c1);
            }
            __builtin_amdgcn_s_setprio(1);
#pragma unroll
            for (int mf = 0; mf < 4; mf++)
#pragma unroll
            for (int qn = 0; qn < 2; qn++)
#pragma unroll
            for (int nf = 0; nf < 2; nf++) {
                MM(4 + mf, qn * 2 + nf, af[mf][0], bfrg[qn][nf][0]);
                MM(4 + mf, qn * 2 + nf, af[mf][1], bfrg[qn][nf][1]);
            }
            __builtin_amdgcn_s_setprio(0);
        }
        __builtin_amdgcn_s_barrier();
        __builtin_amdgcn_sched_barrier(0);
    }
#undef MM

#pragma unroll
    for (int qm = 0; qm < 2; qm++)
#pragma unroll
    for (int mf = 0; mf < 4; mf++) {
        const int row = m0 + wm * 128 + qm * 64 + mf * 16 + l4 * 4;
#pragma unroll
        for (int qn = 0; qn < 2; qn++)
#pragma unroll
        for (int nf = 0; nf < 2; nf++) {
            const int col = n0 + wn * 64 + qn * 32 + nf * 16 + l15;
            const float bv = (MODE == 2) ? bias[col] : 0.0f;
            const f32x4 av = acc[qm * 4 + mf][qn * 2 + nf];
#pragma unroll
            for (int r = 0; r < 4; r++) {
                const float v = av[r] * alpha + bv;
                if (MODE == 1) {
                    ((unsigned short*)C)[(size_t)z * sC + (size_t)(row + r) * ldc + col] = f2bf(v);
                } else {
                    const int lc = col & 1023;
                    if (col < 2048)
                        ((unsigned short*)C)[(size_t)(col >> 10) * 8388608 +
                                             (size_t)(row + r) * 1024 + lc] = f2bf(v);
                    else
                        Vp[(size_t)(row + r) * 1024 + lc] = f2bf(v);
                }
            }
        }
    }
}

// ============================================================================
// PV GEMM: 256x128 tile, BK=64, 8 waves (2M x 4N, per-wave 128x32), 512 thr,
// 2-phase k_g256-style schedule, fp32 out.  Grid (N/128, M/256, z) = 256
// blocks = 1/CU.  LDS 96 KB: As 2x32KB (256x64), Bs 2x16KB (128x64).
// 6 stage instrs/tile (A:4, B:2).  Ledger: P1 issues 3 of t+1 then vmcnt(3)
// (drains cur's remaining 3, keeps 3 in flight); P2 issues other 3.
// Last tile: vmcnt(0) at P1.  acc f32x4[8][2] = 64 AGPR; arch live ~70.
// ============================================================================
__global__ __launch_bounds__(512, 2) void k_pv256(
        const unsigned short* __restrict__ A, int lda,
        const unsigned short* __restrict__ Bt, int ldb,
        float* __restrict__ C, int ldc,
        int K, long sA, long sB, long sC) {
    __shared__ __align__(16) unsigned short As[2][16384];   // 256x64
    __shared__ __align__(16) unsigned short Bs[2][8192];    // 128x64

    const int z = blockIdx.z;
    A  += (size_t)z * sA;
    Bt += (size_t)z * sB;

    const int nwg  = gridDim.x * gridDim.y;      // 128, %8==0
    const int flat = blockIdx.y * gridDim.x + blockIdx.x;
    const int swzb = (flat & 7) * (nwg >> 3) + (flat >> 3);
    const int m0   = (swzb / gridDim.x) * 256;
    const int n0   = (swzb % gridDim.x) * 128;

    const int tid  = threadIdx.x;
    const int lane = tid & 63;
    const int wid  = tid >> 6;      // 0..7
    const int wm   = wid >> 2;      // 0..1
    const int wn   = wid & 3;       // 0..3
    const int l15  = lane & 15;
    const int l4   = lane >> 4;

    f32x4 acc[8][2] = {};           // 64 AGPR

    const int srow = tid >> 3;                              // 0..63
    const int kel  = (((lane & 7) ^ (lane >> 3)) << 3);
    const int c0 = ((l4 << 4)) ^ ((l15 & 7) << 4);
    const int c1 = (64 + (l4 << 4)) ^ ((l15 & 7) << 4);

    auto stageA1 = [&](int b, int a, int kt) {              // one instr: rows a*64..+63
        const int r = a * 64 + srow;
        gload_lds16(A + (size_t)(m0 + r) * lda + kt * 64 + kel,
                    (char*)As + b * 32768 + a * 8192 + (wid << 10));
    };
    auto stageB1 = [&](int b, int c, int kt) {              // one instr: rows c*64..+63
        const int r = c * 64 + srow;
        gload_lds16(Bt + (size_t)(n0 + r) * ldb + kt * 64 + kel,
                    (char*)Bs + b * 16384 + c * 8192 + (wid << 10));
    };

#define MM(I, J, X, Y) \
    acc[I][J] = __builtin_amdgcn_mfma_f32_16x16x32_bf16((X), (Y), acc[I][J], 0, 0, 0)

    const int NT = K >> 6;
    // prologue: all 6 of tile 0
    stageA1(0, 0, 0); stageA1(0, 1, 0); stageA1(0, 2, 0); stageA1(0, 3, 0);
    stageB1(0, 0, 0); stageB1(0, 1, 0);

    for (int t = 0; t < NT; t++) {
        const int cur = t & 1, nxt = cur ^ 1;
        const char* Ab = (const char*)As + cur * 32768;
        const char* Bb = (const char*)Bs + cur * 16384;

        // ---------- P1 ----------
        if (t + 1 < NT) {
            stageA1(nxt, 0, t + 1); stageA1(nxt, 1, t + 1); stageB1(nxt, 0, t + 1);
            WAITVM(3);
        } else {
            WAITVM(0);
        }
        __builtin_amdgcn_s_barrier();
        __builtin_amdgcn_sched_barrier(0);

        bf16x8 bfrg[2][2];      // [nf][kk], resident both phases
#pragma unroll
        for (int nf = 0; nf < 2; nf++) {
            const int rb = (wn * 32 + nf * 16 + l15) * 128;
            bfrg[nf][0] = *(const bf16x8*)(Bb + rb + c0);
            bfrg[nf][1] = *(const bf16x8*)(Bb + rb + c1);
        }
        {
            bf16x8 af[4][2];
#pragma unroll
            for (int mf = 0; mf < 4; mf++) {
                const int ra = (wm * 128 + 0 * 64 + mf * 16 + l15) * 128;
                af[mf][0] = *(const bf16x8*)(Ab + ra + c0);
                af[mf][1] = *(const bf16x8*)(Ab + ra + c1);
            }
            __builtin_amdgcn_s_setprio(1);
#pragma unroll
            for (int mf = 0; mf < 4; mf++)
#pragma unroll
            for (int nf = 0; nf < 2; nf++) {
                MM(mf, nf, af[mf][0], bfrg[nf][0]);
                MM(mf, nf, af[mf][1], bfrg[nf][1]);
            }
            __builtin_amdgcn_s_setprio(0);
        }

        // ---------- P2 ----------
        if (t + 1 < NT) {
            stageA1(nxt, 2, t + 1); stageA1(nxt, 3, t + 1); stageB1(nxt, 1, t + 1);
        }
        {
            bf16x8 af[4][2];
#pragma unroll
            for (int mf = 0; mf < 4; mf++) {
                const int ra = (wm * 128 + 1 * 64 + mf * 16 + l15) * 128;
                af[mf][0] = *(const bf16x8*)(Ab + ra + c0);
                af[mf][1] = *(const bf16x8*)(Ab + ra + c1);
            }
            __builtin_amdgcn_s_setprio(1);
#pragma unroll
            for (int mf = 0; mf < 4; mf++)
#pragma unroll
            for (int nf = 0; nf < 2; nf++) {
                MM(4 + mf, nf, af[mf][0], bfrg[nf][0]);
                MM(4 + mf, nf, af[mf][1], bfrg[nf][1]);
            }
            __builtin_amdgcn_s_setprio(0);
        }
        __builtin_amdgcn_s_barrier();
        __builtin_amdgcn_sched_barrier(0);
    }
#undef MM

    // epilogue: fp32 store
#pragma unroll
    for (int qm = 0; qm < 2; qm++)
#pragma unroll
    for (int mf = 0; mf < 4; mf++) {
        const int row = m0 + wm * 128 + qm * 64 + mf * 16 + l4 * 4;
#pragma unroll
        for (int nf = 0; nf < 2; nf++) {
            const int col = n0 + wn * 32 + nf * 16 + l15;
            const f32x4 av = acc[qm * 4 + mf][nf];
#pragma unroll
            for (int r = 0; r < 4; r++)
                C[(size_t)z * sC + (size_t)(row + r) * ldc + col] = av[r];
        }
    }
}

// ---------- in-place row softmax on bf16 scores [rows][S=4096] ----------
__global__ __launch_bounds__(256) void k_softmax_inplace(unsigned short* __restrict__ P, int S) {
    __shared__ float red[8];
    const int row  = blockIdx.x;
    const int tid  = threadIdx.x;
    const int lane = tid & 63;
    const int wid  = tid >> 6;
    unsigned short* p = P + (size_t)row * S;

    float v[16];
    u16x8 h0 = *(const u16x8*)&p[tid * 16];
    u16x8 h1 = *(const u16x8*)&p[tid * 16 + 8];
    float mx = -1e30f;
#pragma unroll
    for (int j = 0; j < 8; j++) { v[j]     = bf2f(h0[j]); mx = fmaxf(mx, v[j]);     }
#pragma unroll
    for (int j = 0; j < 8; j++) { v[j + 8] = bf2f(h1[j]); mx = fmaxf(mx, v[j + 8]); }

#pragma unroll
    for (int o = 32; o >= 1; o >>= 1) mx = fmaxf(mx, __shfl_xor(mx, o));
    if (lane == 0) red[wid] = mx;
    __syncthreads();
    mx = fmaxf(fmaxf(red[0], red[1]), fmaxf(red[2], red[3]));

    float sum = 0.0f;
#pragma unroll
    for (int j = 0; j < 16; j++) { v[j] = __expf(v[j] - mx); sum += v[j]; }
#pragma unroll
    for (int o = 32; o >= 1; o >>= 1) sum += __shfl_xor(sum, o);
    if (lane == 0) red[4 + wid] = sum;
    __syncthreads();
    sum = red[4] + red[5] + red[6] + red[7];
    const float rinv = 1.0f / sum;

    u16x8 o0, o1;
#pragma unroll
    for (int j = 0; j < 8; j++) { o0[j] = f2bf(v[j] * rinv); o1[j] = f2bf(v[j + 8] * rinv); }
    *(u16x8*)&p[tid * 16]     = o0;
    *(u16x8*)&p[tid * 16 + 8] = o1;
}

// ---------- launch ----------
extern "C" void kernel_launch(void* const* d_in, const int* in_sizes, int n_in,
                              void* d_out, int out_size, void* d_ws, size_t ws_size,
                              hipStream_t stream) {
    const float* x    = (const float*)d_in[0];   // [2,4096,1024]
    const float* W    = (const float*)d_in[1];   // [1024,3072]
    const float* bias = (const float*)d_in[2];   // [3072]
    float* out        = (float*)d_out;           // [2,4096,1024]

    // ws layout (MB):  Qb@0(16)  Kb@16(16)  Vt@32(16)  xb@48(16)  Wt@64(6)  Vrow@70(16)
    // Pcat@48(64) overlays dead xb/Wt/Vrow after GEMM1+transpose_v.  Peak 112 MB.
    char* ws = (char*)d_ws;
    unsigned short* Qb   = (unsigned short*)(ws);
    unsigned short* Vt   = (unsigned short*)(ws + 33554432);
    unsigned short* xb   = (unsigned short*)(ws + 50331648);
    unsigned short* Wt   = (unsigned short*)(ws + 67108864);
    unsigned short* Vrow = (unsigned short*)(ws + 73400320);
    unsigned short* Pcat = (unsigned short*)(ws + 50331648);

    // 1. x -> bf16
    k_f32_to_bf16<<<8192, 256, 0, stream>>>(x, xb, (8192 * 1024) / 4);
    // 2. W -> Wt (bf16, transposed)
    k_transpose_w<<<dim3(96, 32), dim3(32, 8), 0, stream>>>(W, Wt, 1024, 3072);
    // 3. qkv = x*W + b  (M=8192, N=3072, K=1024), routed into Qb|Kb|Vrow
    k_g256<2><<<dim3(12, 32, 1), 512, 0, stream>>>(
        xb, 1024, Wt, 1024, (void*)Qb, 1024, Vrow, bias, 1024, 1.0f, 0, 0, 0);
    // 4. Vrow -> Vt
    k_transpose_v<<<dim3(128, 32, 2), dim3(32, 8), 0, stream>>>(Vrow, Vt);

    const float scale = 0.03125f;  // 1/sqrt(1024)
    // 5. scores = Q*K^T * scale  (M=N=4096, K=1024, z=2) -> bf16 Pcat
    k_g256<1><<<dim3(16, 16, 2), 512, 0, stream>>>(
        Qb, 1024, Qb + 8388608, 1024, (void*)Pcat, 4096, nullptr, nullptr,
        1024, scale, 4194304, 4194304, 16777216);
    // 6. row softmax in place (8192 rows)
    k_softmax_inplace<<<8192, 256, 0, stream>>>(Pcat, 4096);
    // 7. out = P * V  (M=4096, N=1024 -> BN=128, K=4096, z=2) -> fp32
    k_pv256<<<dim3(8, 16, 2), 512, 0, stream>>>(
        Pcat, 4096, Vt, 4096, out, 1024, 4096, 16777216, 4194304, 4194304);
}